// Round 18
// baseline (188.813 us; speedup 1.0000x reference)
//
#include <hip/hip_runtime.h>
#include <stdint.h>

// B=2, S=2048, D=1024, H=16, HD=64
typedef unsigned short u16;
typedef unsigned int u32;
typedef unsigned long long u64;
typedef __bf16 bf16x8 __attribute__((ext_vector_type(8)));
typedef float f32x4 __attribute__((ext_vector_type(4)));
typedef unsigned short u16x8 __attribute__((ext_vector_type(8)));
typedef unsigned short u16x4 __attribute__((ext_vector_type(4)));
typedef unsigned int u32x4 __attribute__((ext_vector_type(4)));

#define QSCALE 0.1803368801111204f  // 0.125 * log2(e): folded into Wq/bq so softmax uses exp2

static __device__ __forceinline__ u16 f2bf(float f) {
  unsigned u = __builtin_bit_cast(unsigned, f);
  u += 0x7fffu + ((u >> 16) & 1u);   // RNE
  return (u16)(u >> 16);
}

static __device__ __forceinline__ bf16x8 ldfrag(const u16* p) {
  return *reinterpret_cast<const bf16x8*>(p);
}

static __device__ __forceinline__ void gll16(const u16* g, u16* l) {
  __builtin_amdgcn_global_load_lds(
      (const __attribute__((address_space(1))) void*)g,
      (__attribute__((address_space(3))) void*)l, 16, 0, 0);
}

// pinned 16B global load -> VGPRs. asm volatile so the compiler can NOT sink or
// rematerialize it (plain loads from const-__restrict__ memory get sunk past the
// barrier asm — the R15 failure). Completion is covered by the explicit vmcnt(0).
static __device__ __forceinline__ u32x4 gload16_asm(const u16* p) {
  u32x4 r;
  asm volatile("global_load_dwordx4 %0, %1, off" : "=v"(r) : "v"(p));
  return r;
}

static __device__ __forceinline__ u32 cvt_pk_bf16(float lo, float hi) {
  u32 r;
  asm("v_cvt_pk_bf16_f32 %0, %1, %2" : "=v"(r) : "v"(lo), "v"(hi));
  return r;
}

// raw v_exp_f32 (2^x): avoids the non-fast-math denormal-guard expansion of exp2f.
static __device__ __forceinline__ float fexp2(float x) {
  return __builtin_amdgcn_exp2f(x);
}

// 3-ary max (clang fuses to v_max3_f32)
static __device__ __forceinline__ float fm3(float a, float b, float c) {
  return fmaxf(fmaxf(a, b), c);
}

// ---------------- prep: cast x (blocks 0..2047) + transpose W (blocks 2048..3071) ----------
__global__ __launch_bounds__(256) void prep_kernel(
    const float* __restrict__ x,
    const float* __restrict__ Wq, const float* __restrict__ Wk,
    const float* __restrict__ Wv, const float* __restrict__ Wo,
    u16* __restrict__ xb, u16* __restrict__ WT) {
  __shared__ float tile[64][65];
  int bid = blockIdx.x;
  int t = threadIdx.x;
  if (bid < 2048) {
    int i = (bid * 256 + t) * 8;
    const float4* p = reinterpret_cast<const float4*>(x + i);
    float4 a = p[0], b = p[1];
    u16x8 o;
    o[0] = f2bf(a.x); o[1] = f2bf(a.y); o[2] = f2bf(a.z); o[3] = f2bf(a.w);
    o[4] = f2bf(b.x); o[5] = f2bf(b.y); o[6] = f2bf(b.z); o[7] = f2bf(b.w);
    *reinterpret_cast<u16x8*>(xb + i) = o;
    return;
  }
  int r0 = bid - 2048;
  int z = r0 >> 8, rem = r0 & 255;
  int n0 = (rem & 15) * 64, k0 = (rem >> 4) * 64;
  const float* W = (z == 0) ? Wq : (z == 1) ? Wk : (z == 2) ? Wv : Wo;
  float wscale = (z == 0) ? QSCALE : 1.0f;
  u16* out = WT + (size_t)z * 1024 * 1024;
  int rr = t >> 4;         // 0..15
  int cc = (t & 15) * 4;   // 0..60
#pragma unroll
  for (int j = 0; j < 4; ++j) {
    int r = rr + 16 * j;
    float4 v = *reinterpret_cast<const float4*>(W + (size_t)(k0 + r) * 1024 + n0 + cc);
    tile[r][cc + 0] = v.x; tile[r][cc + 1] = v.y;
    tile[r][cc + 2] = v.z; tile[r][cc + 3] = v.w;
  }
  __syncthreads();
#pragma unroll
  for (int j = 0; j < 4; ++j) {
    int nl = rr + 16 * j;
    u16x4 o;
#pragma unroll
    for (int i2 = 0; i2 < 4; ++i2) o[i2] = f2bf(tile[cc + i2][nl] * wscale);
    *reinterpret_cast<u16x4*>(out + (size_t)(n0 + nl) * 1024 + k0 + cc) = o;
  }
}

// ---------------- QKV GEMM body: 512 threads, 8 waves (4m x 2n), 32x64 per wave --------
// Triple-buffered A/B staging with counted vmcnt(2) before raw s_barrier.
template <int MODE>
static __device__ __forceinline__ void qkv_body(
    u16* smem, const u16* __restrict__ A, const u16* __restrict__ Wt,
    const float* __restrict__ bias, float bscale, u16* __restrict__ Out) {
  int t = threadIdx.x;
  int lane = t & 63, wave = t >> 6;          // 8 waves
  int g = lane >> 4, c = lane & 15;
  int m0 = blockIdx.y * 128, n0 = blockIdx.x * 128;
  int wm = (wave >> 1) * 32, wn = (wave & 1) * 64;

  f32x4 acc[2][4] = {};

  const u16* Ag = A + (size_t)(m0 + (t >> 2)) * 1024 + (t & 3) * 8;
  const u16* Bg = Wt + (size_t)(n0 + (t >> 2)) * 1024 + (t & 3) * 8;

  u16* dstA = smem + t * 8;
  u16* dstB = smem + 4096 + t * 8;
  const int afo = (wm + c) * 32 + g * 8;
  const int bfo = 4096 + (wn + c) * 32 + g * 8;

  gll16(Ag, dstA);
  gll16(Bg, dstB);
  gll16(Ag + 32, dstA + 8192);
  gll16(Bg + 32, dstB + 8192);
  asm volatile("s_waitcnt vmcnt(2)" ::: "memory");
  __builtin_amdgcn_s_barrier();
  asm volatile("" ::: "memory");

  int cur = 0;
  for (int st = 0; st < 32; ++st) {
    if (st <= 29) {
      int nb = cur + 2; if (nb >= 3) nb -= 3;
      gll16(Ag + (st + 2) * 32, dstA + nb * 8192);
      gll16(Bg + (st + 2) * 32, dstB + nb * 8192);
    }
    const u16* buf = smem + cur * 8192;
    bf16x8 af[2], bfr[4];
#pragma unroll
    for (int i = 0; i < 2; ++i) af[i] = ldfrag(buf + afo + 16 * i * 32);
#pragma unroll
    for (int j = 0; j < 4; ++j) bfr[j] = ldfrag(buf + bfo + 16 * j * 32);
    __builtin_amdgcn_s_setprio(1);
#pragma unroll
    for (int i = 0; i < 2; ++i)
#pragma unroll
      for (int j = 0; j < 4; ++j) {
        if (MODE == 2)
          acc[i][j] = __builtin_amdgcn_mfma_f32_16x16x32_bf16(af[i], bfr[j], acc[i][j], 0, 0, 0);
        else
          acc[i][j] = __builtin_amdgcn_mfma_f32_16x16x32_bf16(bfr[j], af[i], acc[i][j], 0, 0, 0);
      }
    __builtin_amdgcn_s_setprio(0);

    if (st <= 29)
      asm volatile("s_waitcnt vmcnt(2)" ::: "memory");
    else if (st == 30)
      asm volatile("s_waitcnt vmcnt(0)" ::: "memory");
    if (st < 31) {
      __builtin_amdgcn_s_barrier();
      asm volatile("" ::: "memory");
    }
    ++cur; if (cur == 3) cur = 0;
  }

  if (MODE == 0) {
    // swapped: acc[i][j][r] = C[m = wm+16i+c][n = wn+16j+4g+r]
    int nj[4], hj[4], dj[4];
    f32x4 bbj[4];
#pragma unroll
    for (int j = 0; j < 4; ++j) {
      nj[j] = n0 + wn + 16 * j + 4 * g;
      hj[j] = nj[j] >> 6; dj[j] = nj[j] & 63;
      f32x4 bb = *reinterpret_cast<const f32x4*>(&bias[nj[j]]);
#pragma unroll
      for (int r = 0; r < 4; ++r) bbj[j][r] = bb[r] * bscale;
    }
#pragma unroll
    for (int i = 0; i < 2; ++i) {
      int m = m0 + wm + 16 * i + c;
      int b2 = m >> 11, s2 = m & 2047;
#pragma unroll
      for (int j = 0; j < 4; ++j) {
        u16x4 o4;
#pragma unroll
        for (int r = 0; r < 4; ++r) o4[r] = f2bf(acc[i][j][r] + bbj[j][r]);
        *reinterpret_cast<u16x4*>(
            Out + ((size_t)(b2 * 16 + hj[j]) * 2048 + s2) * 64 + dj[j]) = o4;
      }
    }
  } else {
    // V^T: unswapped acc[i][j][r] = C[s_local = wm+16i+4g+r][n_local = wn+16j+c]
    float bvj[4];
#pragma unroll
    for (int j = 0; j < 4; ++j) bvj[j] = bias[n0 + wn + 16 * j + c];
    u16* tb = smem;                       // tb[n_local 128][s_half 64 pad 72]
    int b2 = m0 >> 11, s0 = m0 & 2047;
    int rdrow = t >> 3;                   // 0..63
    int slot = t & 7;
    int sh_base = ((wave >> 1) & 1) * 32;
    __syncthreads();
#pragma unroll
    for (int half = 0; half < 2; ++half) {
      if ((wave >> 2) == half) {
#pragma unroll
        for (int i = 0; i < 2; ++i)
#pragma unroll
          for (int j = 0; j < 4; ++j) {
            u16x4 o4;
#pragma unroll
            for (int r = 0; r < 4; ++r) o4[r] = f2bf(acc[i][j][r] + bvj[j]);
            *reinterpret_cast<u16x4*>(
                &tb[(wn + 16 * j + c) * 72 + sh_base + 16 * i + 4 * g]) = o4;
          }
      }
      __syncthreads();
#pragma unroll
      for (int k = 0; k < 2; ++k) {
        int row = rdrow + 64 * k;
        u16x8 v = *reinterpret_cast<const u16x8*>(&tb[row * 72 + slot * 8]);
        int n = n0 + row, h2 = n >> 6, d2 = n & 63;
        *reinterpret_cast<u16x8*>(
            Out + ((size_t)(b2 * 16 + h2) * 64 + d2) * 2048 + s0 + half * 64 + slot * 8) = v;
      }
      if (half == 0) __syncthreads();
    }
  }
}

__global__ __launch_bounds__(512) void qkv_gemm_kernel(
    const u16* __restrict__ xb, const u16* __restrict__ WT,
    const float* __restrict__ bq, const float* __restrict__ bk,
    const float* __restrict__ bv,
    u16* __restrict__ Q, u16* __restrict__ K, u16* __restrict__ V) {
  __shared__ u16 smem[24576];   // 3 x (As 4096 + Bs 4096); tb[128*72] overlays
  int z = blockIdx.z;
  if (z == 0)      qkv_body<0>(smem, xb, WT, bq, QSCALE, Q);
  else if (z == 1) qkv_body<0>(smem, xb, WT + (size_t)1024 * 1024, bk, 1.0f, K);
  else             qkv_body<2>(smem, xb, WT + (size_t)2 * 1024 * 1024, bv, 1.0f, V);
}

// ---------------- out-projection: 512 threads, pipelined like qkv, fp32 out ----------------
__global__ __launch_bounds__(512) void oproj_kernel(
    const u16* __restrict__ A, const u16* __restrict__ Wt,
    const float* __restrict__ bias, float* __restrict__ out) {
  __shared__ u16 smem[24576];
  int t = threadIdx.x;
  int lane = t & 63, wave = t >> 6;          // 8 waves
  int g = lane >> 4, c = lane & 15;
  int m0 = blockIdx.y * 128, n0 = blockIdx.x * 128;
  int wm = (wave >> 1) * 32, wn = (wave & 1) * 64;

  f32x4 acc[2][4] = {};

  const u16* Ag = A + (size_t)(m0 + (t >> 2)) * 1024 + (t & 3) * 8;
  const u16* Bg = Wt + (size_t)(n0 + (t >> 2)) * 1024 + (t & 3) * 8;
  u16* dstA = smem + t * 8;
  u16* dstB = smem + 4096 + t * 8;
  const int afo = (wm + c) * 32 + g * 8;
  const int bfo = 4096 + (wn + c) * 32 + g * 8;

  gll16(Ag, dstA);
  gll16(Bg, dstB);
  gll16(Ag + 32, dstA + 8192);
  gll16(Bg + 32, dstB + 8192);
  asm volatile("s_waitcnt vmcnt(2)" ::: "memory");
  __builtin_amdgcn_s_barrier();
  asm volatile("" ::: "memory");

  int cur = 0;
  for (int st = 0; st < 32; ++st) {
    if (st <= 29) {
      int nb = cur + 2; if (nb >= 3) nb -= 3;
      gll16(Ag + (st + 2) * 32, dstA + nb * 8192);
      gll16(Bg + (st + 2) * 32, dstB + nb * 8192);
    }
    const u16* buf = smem + cur * 8192;
    bf16x8 af[2], bfr[4];
#pragma unroll
    for (int i = 0; i < 2; ++i) af[i] = ldfrag(buf + afo + 16 * i * 32);
#pragma unroll
    for (int j = 0; j < 4; ++j) bfr[j] = ldfrag(buf + bfo + 16 * j * 32);
    __builtin_amdgcn_s_setprio(1);
#pragma unroll
    for (int i = 0; i < 2; ++i)
#pragma unroll
      for (int j = 0; j < 4; ++j)
        acc[i][j] = __builtin_amdgcn_mfma_f32_16x16x32_bf16(bfr[j], af[i], acc[i][j], 0, 0, 0);
    __builtin_amdgcn_s_setprio(0);

    if (st <= 29)
      asm volatile("s_waitcnt vmcnt(2)" ::: "memory");
    else if (st == 30)
      asm volatile("s_waitcnt vmcnt(0)" ::: "memory");
    if (st < 31) {
      __builtin_amdgcn_s_barrier();
      asm volatile("" ::: "memory");
    }
    ++cur; if (cur == 3) cur = 0;
  }

  f32x4 bbj[4];
#pragma unroll
  for (int j = 0; j < 4; ++j)
    bbj[j] = *reinterpret_cast<const f32x4*>(&bias[n0 + wn + 16 * j + 4 * g]);
#pragma unroll
  for (int i = 0; i < 2; ++i) {
    int m = m0 + wm + 16 * i + c;
#pragma unroll
    for (int j = 0; j < 4; ++j) {
      f32x4 v = acc[i][j] + bbj[j];
      *reinterpret_cast<f32x4*>(out + (size_t)m * 1024 + n0 + wn + 16 * j + 4 * g) = v;
    }
  }
}

// ---------------- flash attention: 8 waves x 16q, KVBLK=64, K via pinned asm loads --------
// LDS pipe was 96% saturated (18 b128 reads/wave-tile). K-frag LDS reads (8 of 18) are
// 16x-redundant per CU and K is L2-resident (XCD swizzle) -> load K straight to registers
// with asm volatile global_load_dwordx4 (pinned: can't be sunk/rematerialized like the
// plain loads of R15). Issued after QK(t), drained by vmcnt(0) at tile end, used at
// QK(t+1). V stays gll16 -> LDS double-buffered. LDS 24 KB; grid 512 = 2 blk/CU.
__global__ __launch_bounds__(512) void attn_kernel(
    const u16* __restrict__ Q, const u16* __restrict__ K,
    const u16* __restrict__ V, u16* __restrict__ attn) {
  __shared__ u16 Vt[2][4096];
  __shared__ u16 Pf[8][512];   // per-wave 1KB: 16q x 32kv bf16 (reused across m-halves)

  const int t = threadIdx.x;
  const int lane = t & 63, w = t >> 6;       // 8 waves
  const int g = lane >> 4, c = lane & 15;

  // XCD-aware bijective swizzle (nwg=512): each XCD's 64 blocks cover 4 (b,h) pairs
  int flat = blockIdx.x + 16 * (blockIdx.y + 16 * blockIdx.z);
  int sw = (flat & 7) * 64 + (flat >> 3);
  const int b = sw >> 8, h = (sw >> 4) & 15, q0 = (sw & 15) * 128;

  const u16* Qh = Q + ((size_t)(b * 16 + h) * 2048) * 64;
  const u16* Kh = K + ((size_t)(b * 16 + h) * 2048) * 64;
  const u16* VTh = V + ((size_t)(b * 16 + h) * 64) * 2048;

  const int qw = q0 + w * 16;
  bf16x8 qf0 = ldfrag(Qh + (size_t)(qw + c) * 64 + 8 * g);
  bf16x8 qf1 = ldfrag(Qh + (size_t)(qw + c) * 64 + 32 + 8 * g);

  bf16x8 ones;
  {
    u16x8 tmp;
#pragma unroll
    for (int l = 0; l < 8; ++l) tmp[l] = 0x3F80;
    ones = __builtin_bit_cast(bf16x8, tmp);
  }

  // K A-frag gather base: lane (g,c), frag (t4,u) <- K[kv0 + 16*t4 + c][32*u + 8*g ..+7]
  const u16* kbase = Kh + (size_t)c * 64 + 8 * g;   // + t4*1024 + u*32 + tile*4096

  // V^T staging (1 gll16/thread/tile): wave w covers d rows [8w, 8w+8)
  const u16* vsrc = VTh + (size_t)(8 * w + (lane >> 3)) * 2048 +
                    (((lane & 7) ^ ((lane >> 3) & 7)) * 8);
  u16* vdst = (u16*)&Vt[0][0] + t * 8;   // + buf*4096

  int vb_off[2];
#pragma unroll
  for (int m = 0; m < 2; ++m)
    vb_off[m] = c * 64 + (((4 * m + g) ^ (c & 7)) * 8);
  const int pa_off = (g * 16 + c) * 8;

  f32x4 o[4] = {};
  f32x4 lsum = {};
  float mrow = -3e38f;

  // ---- prologue: V tile 0 -> LDS; K tile 0 -> registers (pinned loads) ----
  gll16(vsrc, vdst);
  u32x4 kr[4][2];
#pragma unroll
  for (int t4 = 0; t4 < 4; ++t4)
#pragma unroll
    for (int u = 0; u < 2; ++u)
      kr[t4][u] = gload16_asm(kbase + t4 * 1024 + u * 32);
  asm volatile("s_waitcnt vmcnt(0)" ::: "memory");
  __builtin_amdgcn_s_barrier();
  asm volatile("" ::: "memory");

  int cur = 0;
  for (int tt = 0; tt < 32; ++tt) {
    // ---- swapped QK^T: st[t4] = K(16 kv) . Q^T (kr in registers) ----
    f32x4 st[4];
    __builtin_amdgcn_s_setprio(1);
#pragma unroll
    for (int t4 = 0; t4 < 4; ++t4) {
      f32x4 acc = {};
      acc = __builtin_amdgcn_mfma_f32_16x16x32_bf16(
          __builtin_bit_cast(bf16x8, kr[t4][0]), qf0, acc, 0, 0, 0);
      st[t4] = __builtin_amdgcn_mfma_f32_16x16x32_bf16(
          __builtin_bit_cast(bf16x8, kr[t4][1]), qf1, acc, 0, 0, 0);
    }
    __builtin_amdgcn_s_setprio(0);

    if (tt < 31) {
      // V(t+1) -> LDS (other buffer); K(t+1) -> kr via pinned asm loads.
      // Issue-to-wait distance = softmax + pack + PV >> L2 latency.
      gll16(vsrc + (size_t)(tt + 1) * 64, vdst + (cur ^ 1) * 4096);
      const u16* kb2 = kbase + (size_t)(tt + 1) * 4096;
#pragma unroll
      for (int t4 = 0; t4 < 4; ++t4)
#pragma unroll
        for (int u = 0; u < 2; ++u)
          kr[t4][u] = gload16_asm(kb2 + t4 * 1024 + u * 32);
    }

    // ---- online softmax over 64-kv tile (scores already in log2 units) ----
    float u1 = fm3(fm3(st[0][0], st[0][1], st[0][2]),
                   fm3(st[0][3], st[1][0], st[1][1]),
                   fm3(st[1][2], st[1][3], st[2][0]));
    float u2 = fm3(fm3(st[2][1], st[2][2], st[2][3]),
                   fm3(st[3][0], st[3][1], st[3][2]), st[3][3]);
    float tm = fmaxf(u1, u2);
    tm = fmaxf(tm, __shfl_xor(tm, 16));
    tm = fmaxf(tm, __shfl_xor(tm, 32));
    // T13 defer-max: only rescale when the max grew by >8 (log2 units; P <= 2^8)
    const bool grow = __any(tm > mrow + 8.0f);
    if (grow) {
      float nm = fmaxf(mrow, tm);
      float f = fexp2(mrow - nm);
      mrow = nm;
#pragma unroll
      for (int r = 0; r < 4; ++r) {
        float fr = __shfl(f, 4 * g + r);   // f lives at lanes indexed by q=c
        lsum[r] *= fr;
#pragma unroll
        for (int j = 0; j < 4; ++j) o[j][r] *= fr;
      }
    }
#pragma unroll
    for (int t4 = 0; t4 < 4; ++t4)
#pragma unroll
      for (int r = 0; r < 4; ++r) st[t4][r] = fexp2(st[t4][r] - mrow);

    // ---- pack P (per 32-kv half) into per-wave A-frag layout, then PV on that half ----
    u32* pd = (u32*)&Pf[w][0];
#pragma unroll
    for (int m = 0; m < 2; ++m) {
#pragma unroll
      for (int tp = 0; tp < 2; ++tp) {
        int t4 = 2 * m + tp;
        u32 w0 = cvt_pk_bf16(st[t4][0], st[t4][1]);
        u32 w1 = cvt_pk_bf16(st[t4][2], st[t4][3]);
        int gp = (2 * t4 + (g >> 1)) & 3;
        int base = (gp * 16 + c) * 4 + 2 * (g & 1);
        *reinterpret_cast<u64*>(&pd[base]) = (u64)w0 | ((u64)w1 << 32);
      }
      bf16x8 pa = ldfrag(&Pf[w][pa_off]);
      __builtin_amdgcn_s_setprio(1);
#pragma unroll
      for (int j = 0; j < 4; ++j) {
        bf16x8 vb = ldfrag(&Vt[cur][vb_off[m] + j * 1024]);
        o[j] = __builtin_amdgcn_mfma_f32_16x16x32_bf16(pa, vb, o[j], 0, 0, 0);
      }
      lsum = __builtin_amdgcn_mfma_f32_16x16x32_bf16(pa, ones, lsum, 0, 0, 0);
      __builtin_amdgcn_s_setprio(0);
    }

    // drain V(t+1) gll + K(t+1) pinned loads, then cross the barrier with both ready
    if (tt < 31) {
      asm volatile("s_waitcnt vmcnt(0)" ::: "memory");
      __builtin_amdgcn_s_barrier();
      asm volatile("" ::: "memory");
    }
    cur ^= 1;
  }

  // ---- epilogue: normalize, write attn[B,S,D] (O lane layout: q=4g+r, d=16j+c) ----
  float rinv[4];
#pragma unroll
  for (int r = 0; r < 4; ++r) rinv[r] = 1.f / lsum[r];
#pragma unroll
  for (int j = 0; j < 4; ++j)
#pragma unroll
    for (int r = 0; r < 4; ++r) {
      int s = qw + 4 * g + r;
      attn[(size_t)(b * 2048 + s) * 1024 + h * 64 + 16 * j + c] = f2bf(o[j][r] * rinv[r]);
    }
}

extern "C" void kernel_launch(void* const* d_in, const int* in_sizes, int n_in,
                              void* d_out, int out_size, void* d_ws, size_t ws_size,
                              hipStream_t stream) {
  const float* x  = (const float*)d_in[0];
  const float* Wq = (const float*)d_in[1];
  const float* bq = (const float*)d_in[2];
  const float* Wk = (const float*)d_in[3];
  const float* bk = (const float*)d_in[4];
  const float* Wv = (const float*)d_in[5];
  const float* bv = (const float*)d_in[6];
  const float* Wo = (const float*)d_in[7];
  const float* bo = (const float*)d_in[8];
  float* out = (float*)d_out;
  u16* ws = (u16*)d_ws;

  // workspace layout (u16 elems): xb 4M | WT 4x1M | Q 4M | K 4M | V^T 4M  => 40 MB
  u16* xb    = ws;
  u16* WT    = ws + (size_t)4 * 1024 * 1024;
  u16* Qb    = ws + (size_t)8 * 1024 * 1024;
  u16* Kb    = ws + (size_t)12 * 1024 * 1024;
  u16* Vb    = ws + (size_t)16 * 1024 * 1024;
  u16* attnb = xb;  // xb dead after QKV GEMM; reuse for attn output

  prep_kernel<<<3072, 256, 0, stream>>>(x, Wq, Wk, Wv, Wo, xb, WT);
  qkv_gemm_kernel<<<dim3(8, 32, 3), 512, 0, stream>>>(xb, WT, bq, bk, bv, Qb, Kb, Vb);
  attn_kernel<<<dim3(16, 16, 2), 512, 0, stream>>>(Qb, Kb, Vb, attnb);
  oproj_kernel<<<dim3(8, 32), 512, 0, stream>>>(attnb, WT + (size_t)3 * 1024 * 1024, bo, out);
}

// Round 19
// 119.992 us; speedup vs baseline: 1.5735x; 1.5735x over previous
//
#include <hip/hip_runtime.h>
#include <stdint.h>

// B=2, S=2048, D=1024, H=16, HD=64
typedef unsigned short u16;
typedef unsigned int u32;
typedef unsigned long long u64;
typedef __bf16 bf16x8 __attribute__((ext_vector_type(8)));
typedef float f32x4 __attribute__((ext_vector_type(4)));
typedef unsigned short u16x8 __attribute__((ext_vector_type(8)));
typedef unsigned short u16x4 __attribute__((ext_vector_type(4)));

#define QSCALE 0.1803368801111204f  // 0.125 * log2(e): folded into Wq/bq so softmax uses exp2

static __device__ __forceinline__ u16 f2bf(float f) {
  unsigned u = __builtin_bit_cast(unsigned, f);
  u += 0x7fffu + ((u >> 16) & 1u);   // RNE
  return (u16)(u >> 16);
}

static __device__ __forceinline__ bf16x8 ldfrag(const u16* p) {
  return *reinterpret_cast<const bf16x8*>(p);
}

static __device__ __forceinline__ void gll16(const u16* g, u16* l) {
  __builtin_amdgcn_global_load_lds(
      (const __attribute__((address_space(1))) void*)g,
      (__attribute__((address_space(3))) void*)l, 16, 0, 0);
}

static __device__ __forceinline__ u32 cvt_pk_bf16(float lo, float hi) {
  u32 r;
  asm("v_cvt_pk_bf16_f32 %0, %1, %2" : "=v"(r) : "v"(lo), "v"(hi));
  return r;
}

// raw v_exp_f32 (2^x): avoids the non-fast-math denormal-guard expansion of exp2f.
static __device__ __forceinline__ float fexp2(float x) {
  return __builtin_amdgcn_exp2f(x);
}

// 3-ary max (clang fuses to v_max3_f32)
static __device__ __forceinline__ float fm3(float a, float b, float c) {
  return fmaxf(fmaxf(a, b), c);
}

// ---------------- prep: cast x (blocks 0..2047) + transpose W (blocks 2048..3071) ----------
__global__ __launch_bounds__(256) void prep_kernel(
    const float* __restrict__ x,
    const float* __restrict__ Wq, const float* __restrict__ Wk,
    const float* __restrict__ Wv, const float* __restrict__ Wo,
    u16* __restrict__ xb, u16* __restrict__ WT) {
  __shared__ float tile[64][65];
  int bid = blockIdx.x;
  int t = threadIdx.x;
  if (bid < 2048) {
    int i = (bid * 256 + t) * 8;
    const float4* p = reinterpret_cast<const float4*>(x + i);
    float4 a = p[0], b = p[1];
    u16x8 o;
    o[0] = f2bf(a.x); o[1] = f2bf(a.y); o[2] = f2bf(a.z); o[3] = f2bf(a.w);
    o[4] = f2bf(b.x); o[5] = f2bf(b.y); o[6] = f2bf(b.z); o[7] = f2bf(b.w);
    *reinterpret_cast<u16x8*>(xb + i) = o;
    return;
  }
  int r0 = bid - 2048;
  int z = r0 >> 8, rem = r0 & 255;
  int n0 = (rem & 15) * 64, k0 = (rem >> 4) * 64;
  const float* W = (z == 0) ? Wq : (z == 1) ? Wk : (z == 2) ? Wv : Wo;
  float wscale = (z == 0) ? QSCALE : 1.0f;
  u16* out = WT + (size_t)z * 1024 * 1024;
  int rr = t >> 4;         // 0..15
  int cc = (t & 15) * 4;   // 0..60
#pragma unroll
  for (int j = 0; j < 4; ++j) {
    int r = rr + 16 * j;
    float4 v = *reinterpret_cast<const float4*>(W + (size_t)(k0 + r) * 1024 + n0 + cc);
    tile[r][cc + 0] = v.x; tile[r][cc + 1] = v.y;
    tile[r][cc + 2] = v.z; tile[r][cc + 3] = v.w;
  }
  __syncthreads();
#pragma unroll
  for (int j = 0; j < 4; ++j) {
    int nl = rr + 16 * j;
    u16x4 o;
#pragma unroll
    for (int i2 = 0; i2 < 4; ++i2) o[i2] = f2bf(tile[cc + i2][nl] * wscale);
    *reinterpret_cast<u16x4*>(out + (size_t)(n0 + nl) * 1024 + k0 + cc) = o;
  }
}

// ---------------- QKV GEMM body: 512 threads, 8 waves (4m x 2n), 32x64 per wave --------
// Triple-buffered A/B staging with counted vmcnt(2) before raw s_barrier.
template <int MODE>
static __device__ __forceinline__ void qkv_body(
    u16* smem, const u16* __restrict__ A, const u16* __restrict__ Wt,
    const float* __restrict__ bias, float bscale, u16* __restrict__ Out) {
  int t = threadIdx.x;
  int lane = t & 63, wave = t >> 6;          // 8 waves
  int g = lane >> 4, c = lane & 15;
  int m0 = blockIdx.y * 128, n0 = blockIdx.x * 128;
  int wm = (wave >> 1) * 32, wn = (wave & 1) * 64;

  f32x4 acc[2][4] = {};

  const u16* Ag = A + (size_t)(m0 + (t >> 2)) * 1024 + (t & 3) * 8;
  const u16* Bg = Wt + (size_t)(n0 + (t >> 2)) * 1024 + (t & 3) * 8;

  u16* dstA = smem + t * 8;
  u16* dstB = smem + 4096 + t * 8;
  const int afo = (wm + c) * 32 + g * 8;
  const int bfo = 4096 + (wn + c) * 32 + g * 8;

  gll16(Ag, dstA);
  gll16(Bg, dstB);
  gll16(Ag + 32, dstA + 8192);
  gll16(Bg + 32, dstB + 8192);
  asm volatile("s_waitcnt vmcnt(2)" ::: "memory");
  __builtin_amdgcn_s_barrier();
  asm volatile("" ::: "memory");

  int cur = 0;
  for (int st = 0; st < 32; ++st) {
    if (st <= 29) {
      int nb = cur + 2; if (nb >= 3) nb -= 3;
      gll16(Ag + (st + 2) * 32, dstA + nb * 8192);
      gll16(Bg + (st + 2) * 32, dstB + nb * 8192);
    }
    const u16* buf = smem + cur * 8192;
    bf16x8 af[2], bfr[4];
#pragma unroll
    for (int i = 0; i < 2; ++i) af[i] = ldfrag(buf + afo + 16 * i * 32);
#pragma unroll
    for (int j = 0; j < 4; ++j) bfr[j] = ldfrag(buf + bfo + 16 * j * 32);
    __builtin_amdgcn_s_setprio(1);
#pragma unroll
    for (int i = 0; i < 2; ++i)
#pragma unroll
      for (int j = 0; j < 4; ++j) {
        if (MODE == 2)
          acc[i][j] = __builtin_amdgcn_mfma_f32_16x16x32_bf16(af[i], bfr[j], acc[i][j], 0, 0, 0);
        else
          acc[i][j] = __builtin_amdgcn_mfma_f32_16x16x32_bf16(bfr[j], af[i], acc[i][j], 0, 0, 0);
      }
    __builtin_amdgcn_s_setprio(0);

    if (st <= 29)
      asm volatile("s_waitcnt vmcnt(2)" ::: "memory");
    else if (st == 30)
      asm volatile("s_waitcnt vmcnt(0)" ::: "memory");
    if (st < 31) {
      __builtin_amdgcn_s_barrier();
      asm volatile("" ::: "memory");
    }
    ++cur; if (cur == 3) cur = 0;
  }

  if (MODE == 0) {
    // swapped: acc[i][j][r] = C[m = wm+16i+c][n = wn+16j+4g+r]
    int nj[4], hj[4], dj[4];
    f32x4 bbj[4];
#pragma unroll
    for (int j = 0; j < 4; ++j) {
      nj[j] = n0 + wn + 16 * j + 4 * g;
      hj[j] = nj[j] >> 6; dj[j] = nj[j] & 63;
      f32x4 bb = *reinterpret_cast<const f32x4*>(&bias[nj[j]]);
#pragma unroll
      for (int r = 0; r < 4; ++r) bbj[j][r] = bb[r] * bscale;
    }
#pragma unroll
    for (int i = 0; i < 2; ++i) {
      int m = m0 + wm + 16 * i + c;
      int b2 = m >> 11, s2 = m & 2047;
#pragma unroll
      for (int j = 0; j < 4; ++j) {
        u16x4 o4;
#pragma unroll
        for (int r = 0; r < 4; ++r) o4[r] = f2bf(acc[i][j][r] + bbj[j][r]);
        *reinterpret_cast<u16x4*>(
            Out + ((size_t)(b2 * 16 + hj[j]) * 2048 + s2) * 64 + dj[j]) = o4;
      }
    }
  } else {
    // V^T: unswapped acc[i][j][r] = C[s_local = wm+16i+4g+r][n_local = wn+16j+c]
    float bvj[4];
#pragma unroll
    for (int j = 0; j < 4; ++j) bvj[j] = bias[n0 + wn + 16 * j + c];
    u16* tb = smem;                       // tb[n_local 128][s_half 64 pad 72]
    int b2 = m0 >> 11, s0 = m0 & 2047;
    int rdrow = t >> 3;                   // 0..63
    int slot = t & 7;
    int sh_base = ((wave >> 1) & 1) * 32;
    __syncthreads();
#pragma unroll
    for (int half = 0; half < 2; ++half) {
      if ((wave >> 2) == half) {
#pragma unroll
        for (int i = 0; i < 2; ++i)
#pragma unroll
          for (int j = 0; j < 4; ++j) {
            u16x4 o4;
#pragma unroll
            for (int r = 0; r < 4; ++r) o4[r] = f2bf(acc[i][j][r] + bvj[j]);
            *reinterpret_cast<u16x4*>(
                &tb[(wn + 16 * j + c) * 72 + sh_base + 16 * i + 4 * g]) = o4;
          }
      }
      __syncthreads();
#pragma unroll
      for (int k = 0; k < 2; ++k) {
        int row = rdrow + 64 * k;
        u16x8 v = *reinterpret_cast<const u16x8*>(&tb[row * 72 + slot * 8]);
        int n = n0 + row, h2 = n >> 6, d2 = n & 63;
        *reinterpret_cast<u16x8*>(
            Out + ((size_t)(b2 * 16 + h2) * 64 + d2) * 2048 + s0 + half * 64 + slot * 8) = v;
      }
      if (half == 0) __syncthreads();
    }
  }
}

__global__ __launch_bounds__(512) void qkv_gemm_kernel(
    const u16* __restrict__ xb, const u16* __restrict__ WT,
    const float* __restrict__ bq, const float* __restrict__ bk,
    const float* __restrict__ bv,
    u16* __restrict__ Q, u16* __restrict__ K, u16* __restrict__ V) {
  __shared__ u16 smem[24576];   // 3 x (As 4096 + Bs 4096); tb[128*72] overlays
  int z = blockIdx.z;
  if (z == 0)      qkv_body<0>(smem, xb, WT, bq, QSCALE, Q);
  else if (z == 1) qkv_body<0>(smem, xb, WT + (size_t)1024 * 1024, bk, 1.0f, K);
  else             qkv_body<2>(smem, xb, WT + (size_t)2 * 1024 * 1024, bv, 1.0f, V);
}

// ---------------- out-projection: 64x128 tiles, 512 blocks (4 blk/CU), 256 threads ---------
// oproj was 1 block/CU (256 blocks) — parallelism-capped. Halve the tile (64 m x 128 n),
// double the grid: 4 blocks/CU = 16 waves/CU. Same triple-buffer + counted-vmcnt pipeline,
// 3 gll16/thread/K-step (A:1, B:2) -> steady-state vmcnt(3). LDS 3 x 12 KB = 36 KB.
// XCD-bijective swizzle: each XCD's 64 blocks share an A-panel (1 MB) + B (2 MB) in L2.
__global__ __launch_bounds__(256) void oproj_kernel(
    const u16* __restrict__ A, const u16* __restrict__ Wt,
    const float* __restrict__ bias, float* __restrict__ out) {
  __shared__ u16 smem[18432];   // 3 x (A 2048 + B 4096)
  int t = threadIdx.x;
  int lane = t & 63, wave = t >> 6;          // 4 waves
  int g = lane >> 4, c = lane & 15;

  int flat = blockIdx.x + 8 * blockIdx.y;    // 0..511
  int sw = (flat & 7) * 64 + (flat >> 3);
  int m0 = (sw >> 3) * 64, n0 = (sw & 7) * 128;
  int wm = (wave >> 1) * 32, wn = (wave & 1) * 64;

  f32x4 acc[2][4] = {};

  const u16* Ag  = A + (size_t)(m0 + (t >> 2)) * 1024 + (t & 3) * 8;          // 64 rows
  const u16* Bg0 = Wt + (size_t)(n0 + (t >> 2)) * 1024 + (t & 3) * 8;         // rows 0..63
  const u16* Bg1 = Bg0 + (size_t)64 * 1024;                                   // rows 64..127

  u16* dstA  = smem + t * 8;            // A: 2048 u16
  u16* dstB0 = smem + 2048 + t * 8;     // B: 4096 u16
  u16* dstB1 = smem + 4096 + t * 8;
  const int afo = (wm + c) * 32 + g * 8;
  const int bfo = 2048 + (wn + c) * 32 + g * 8;

  // prologue: stage K-steps 0 and 1 (3 loads each); wait step 0 only
  gll16(Ag, dstA);
  gll16(Bg0, dstB0);
  gll16(Bg1, dstB1);
  gll16(Ag + 32, dstA + 6144);
  gll16(Bg0 + 32, dstB0 + 6144);
  gll16(Bg1 + 32, dstB1 + 6144);
  asm volatile("s_waitcnt vmcnt(3)" ::: "memory");
  __builtin_amdgcn_s_barrier();
  asm volatile("" ::: "memory");

  int cur = 0;
  for (int st = 0; st < 32; ++st) {
    if (st <= 29) {
      int nb = cur + 2; if (nb >= 3) nb -= 3;
      gll16(Ag + (st + 2) * 32, dstA + nb * 6144);
      gll16(Bg0 + (st + 2) * 32, dstB0 + nb * 6144);
      gll16(Bg1 + (st + 2) * 32, dstB1 + nb * 6144);
    }
    const u16* buf = smem + cur * 6144;
    bf16x8 af[2], bfr[4];
#pragma unroll
    for (int i = 0; i < 2; ++i) af[i] = ldfrag(buf + afo + 16 * i * 32);
#pragma unroll
    for (int j = 0; j < 4; ++j) bfr[j] = ldfrag(buf + bfo + 16 * j * 32);
    __builtin_amdgcn_s_setprio(1);
#pragma unroll
    for (int i = 0; i < 2; ++i)
#pragma unroll
      for (int j = 0; j < 4; ++j)   // swapped: acc r -> n contiguous
        acc[i][j] = __builtin_amdgcn_mfma_f32_16x16x32_bf16(bfr[j], af[i], acc[i][j], 0, 0, 0);
    __builtin_amdgcn_s_setprio(0);

    if (st <= 29)
      asm volatile("s_waitcnt vmcnt(3)" ::: "memory");
    else if (st == 30)
      asm volatile("s_waitcnt vmcnt(0)" ::: "memory");
    if (st < 31) {
      __builtin_amdgcn_s_barrier();
      asm volatile("" ::: "memory");
    }
    ++cur; if (cur == 3) cur = 0;
  }

  f32x4 bbj[4];
#pragma unroll
  for (int j = 0; j < 4; ++j)
    bbj[j] = *reinterpret_cast<const f32x4*>(&bias[n0 + wn + 16 * j + 4 * g]);
#pragma unroll
  for (int i = 0; i < 2; ++i) {
    int m = m0 + wm + 16 * i + c;
#pragma unroll
    for (int j = 0; j < 4; ++j) {
      f32x4 v = acc[i][j] + bbj[j];
      *reinterpret_cast<f32x4*>(out + (size_t)m * 1024 + n0 + wn + 16 * j + 4 * g) = v;
    }
  }
}

// ---------------- flash attention: 8 waves x 16q = 128 q/block, KVBLK=64 ----------------
// Triple-buffered K/V, 2-tile-ahead prefetch, counted vmcnt(2) BEFORE raw s_barrier
// (loads stay in flight across barriers — T3/T4 pattern). LDS 56 KB, grid 512 = 2 blk/CU.
// Measured best: 60.4 us (VGPR 52, 16 waves/CU). Failed variants: KVBLK=128 (bank
// conflicts 3x), K-in-registers x2 (8x L2 redundancy + load sinking), 32q/wave (occupancy).
__global__ __launch_bounds__(512) void attn_kernel(
    const u16* __restrict__ Q, const u16* __restrict__ K,
    const u16* __restrict__ V, u16* __restrict__ attn) {
  __shared__ u16 Kf[3][4096];
  __shared__ u16 Vt[3][4096];
  __shared__ u16 Pf[8][512];   // per-wave 1KB: 16q x 32kv bf16 (reused across m-halves)

  const int t = threadIdx.x;
  const int lane = t & 63, w = t >> 6;       // 8 waves
  const int g = lane >> 4, c = lane & 15;

  // XCD-aware bijective swizzle (nwg=512): each XCD's 64 blocks cover 4 (b,h) pairs
  int flat = blockIdx.x + 16 * (blockIdx.y + 16 * blockIdx.z);
  int sw = (flat & 7) * 64 + (flat >> 3);
  const int b = sw >> 8, h = (sw >> 4) & 15, q0 = (sw & 15) * 128;

  const u16* Qh = Q + ((size_t)(b * 16 + h) * 2048) * 64;
  const u16* Kh = K + ((size_t)(b * 16 + h) * 2048) * 64;
  const u16* VTh = V + ((size_t)(b * 16 + h) * 64) * 2048;

  const int qw = q0 + w * 16;
  bf16x8 qf0 = ldfrag(Qh + (size_t)(qw + c) * 64 + 8 * g);
  bf16x8 qf1 = ldfrag(Qh + (size_t)(qw + c) * 64 + 32 + 8 * g);

  bf16x8 ones;
  {
    u16x8 tmp;
#pragma unroll
    for (int l = 0; l < 8; ++l) tmp[l] = 0x3F80;
    ones = __builtin_bit_cast(bf16x8, tmp);
  }

  // per-wave staging sources (1 gll16 each for K and V per tile; dest = buf + t*8)
  const u16* ksrc = Kh + (size_t)(16 * ((w >> 1) & 3) + c) * 64 + 32 * (w & 1) + 8 * g;
  const u16* vsrc = VTh + (size_t)(8 * w + (lane >> 3)) * 2048 +
                    (((lane & 7) ^ ((lane >> 3) & 7)) * 8);

  const int koff = g * 128 + c * 8;
  int vb_off[2];
#pragma unroll
  for (int m = 0; m < 2; ++m)
    vb_off[m] = c * 64 + (((4 * m + g) ^ (c & 7)) * 8);
  const int pa_off = (g * 16 + c) * 8;

  f32x4 o[4] = {};
  f32x4 lsum = {};
  float mrow = -3e38f;

  // ---- prologue: stage tiles 0 and 1; wait tile 0 only ----
  gll16(ksrc, &Kf[0][t * 8]);
  gll16(vsrc, &Vt[0][t * 8]);
  gll16(ksrc + 4096, &Kf[1][t * 8]);
  gll16(vsrc + 64, &Vt[1][t * 8]);
  asm volatile("s_waitcnt vmcnt(2)" ::: "memory");
  __builtin_amdgcn_s_barrier();
  asm volatile("" ::: "memory");

  int cur = 0;
  for (int tt32 = 0; tt32 < 32; ++tt32) {
    if (tt32 <= 29) {
      int nb = cur + 2; if (nb >= 3) nb -= 3;
      gll16(ksrc + (size_t)(tt32 + 2) * 4096, &Kf[nb][t * 8]);
      gll16(vsrc + (size_t)(tt32 + 2) * 64, &Vt[nb][t * 8]);
    }

    // ---- swapped QK^T: st[t4] = K(16 kv) . Q^T -> S^T[kv][q], q = c per lane ----
    const u16* kb = &Kf[cur][koff];
    f32x4 st[4];
    __builtin_amdgcn_s_setprio(1);
#pragma unroll
    for (int t4 = 0; t4 < 4; ++t4) {
      f32x4 acc = {};
      acc = __builtin_amdgcn_mfma_f32_16x16x32_bf16(
          ldfrag(kb + t4 * 1024), qf0, acc, 0, 0, 0);
      st[t4] = __builtin_amdgcn_mfma_f32_16x16x32_bf16(
          ldfrag(kb + t4 * 1024 + 512), qf1, acc, 0, 0, 0);
    }
    __builtin_amdgcn_s_setprio(0);

    // ---- online softmax over 64-kv tile (scores already in log2 units) ----
    float u1 = fm3(fm3(st[0][0], st[0][1], st[0][2]),
                   fm3(st[0][3], st[1][0], st[1][1]),
                   fm3(st[1][2], st[1][3], st[2][0]));
    float u2 = fm3(fm3(st[2][1], st[2][2], st[2][3]),
                   fm3(st[3][0], st[3][1], st[3][2]), st[3][3]);
    float tm = fmaxf(u1, u2);
    tm = fmaxf(tm, __shfl_xor(tm, 16));
    tm = fmaxf(tm, __shfl_xor(tm, 32));
    // T13 defer-max: only rescale when the max grew by >8 (log2 units; P <= 2^8)
    const bool grow = __any(tm > mrow + 8.0f);
    if (grow) {
      float nm = fmaxf(mrow, tm);
      float f = fexp2(mrow - nm);
      mrow = nm;
#pragma unroll
      for (int r = 0; r < 4; ++r) {
        float fr = __shfl(f, 4 * g + r);   // f lives at lanes indexed by q=c
        lsum[r] *= fr;
#pragma unroll
        for (int j = 0; j < 4; ++j) o[j][r] *= fr;
      }
    }
#pragma unroll
    for (int t4 = 0; t4 < 4; ++t4)
#pragma unroll
      for (int r = 0; r < 4; ++r) st[t4][r] = fexp2(st[t4][r] - mrow);

    // ---- pack P (per 32-kv half) into per-wave A-frag layout, then PV on that half ----
    u32* pd = (u32*)&Pf[w][0];
#pragma unroll
    for (int m = 0; m < 2; ++m) {
#pragma unroll
      for (int tp = 0; tp < 2; ++tp) {
        int t4 = 2 * m + tp;
        u32 w0 = cvt_pk_bf16(st[t4][0], st[t4][1]);
        u32 w1 = cvt_pk_bf16(st[t4][2], st[t4][3]);
        int gp = (2 * t4 + (g >> 1)) & 3;
        int base = (gp * 16 + c) * 4 + 2 * (g & 1);
        *reinterpret_cast<u64*>(&pd[base]) = (u64)w0 | ((u64)w1 << 32);
      }
      bf16x8 pa = ldfrag(&Pf[w][pa_off]);
      __builtin_amdgcn_s_setprio(1);
#pragma unroll
      for (int j = 0; j < 4; ++j) {
        bf16x8 vb = ldfrag(&Vt[cur][vb_off[m] + j * 1024]);
        o[j] = __builtin_amdgcn_mfma_f32_16x16x32_bf16(pa, vb, o[j], 0, 0, 0);
      }
      lsum = __builtin_amdgcn_mfma_f32_16x16x32_bf16(pa, ones, lsum, 0, 0, 0);
      __builtin_amdgcn_s_setprio(0);
    }

    // counted wait: drain next tile's loads only; keep tile+2 in flight across barrier
    if (tt32 <= 29)
      asm volatile("s_waitcnt vmcnt(2)" ::: "memory");
    else if (tt32 == 30)
      asm volatile("s_waitcnt vmcnt(0)" ::: "memory");
    if (tt32 < 31) {
      __builtin_amdgcn_s_barrier();
      asm volatile("" ::: "memory");
    }
    ++cur; if (cur == 3) cur = 0;
  }

  // ---- epilogue: normalize, write attn[B,S,D] (O lane layout: q=4g+r, d=16j+c) ----
  float rinv[4];
#pragma unroll
  for (int r = 0; r < 4; ++r) rinv[r] = 1.f / lsum[r];
#pragma unroll
  for (int j = 0; j < 4; ++j)
#pragma unroll
    for (int r = 0; r < 4; ++r) {
      int s = qw + 4 * g + r;
      attn[(size_t)(b * 2048 + s) * 1024 + h * 64 + 16 * j + c] = f2bf(o[j][r] * rinv[r]);
    }
}

extern "C" void kernel_launch(void* const* d_in, const int* in_sizes, int n_in,
                              void* d_out, int out_size, void* d_ws, size_t ws_size,
                              hipStream_t stream) {
  const float* x  = (const float*)d_in[0];
  const float* Wq = (const float*)d_in[1];
  const float* bq = (const float*)d_in[2];
  const float* Wk = (const float*)d_in[3];
  const float* bk = (const float*)d_in[4];
  const float* Wv = (const float*)d_in[5];
  const float* bv = (const float*)d_in[6];
  const float* Wo = (const float*)d_in[7];
  const float* bo = (const float*)d_in[8];
  float* out = (float*)d_out;
  u16* ws = (u16*)d_ws;

  // workspace layout (u16 elems): xb 4M | WT 4x1M | Q 4M | K 4M | V^T 4M  => 40 MB
  u16* xb    = ws;
  u16* WT    = ws + (size_t)4 * 1024 * 1024;
  u16* Qb    = ws + (size_t)8 * 1024 * 1024;
  u16* Kb    = ws + (size_t)12 * 1024 * 1024;
  u16* Vb    = ws + (size_t)16 * 1024 * 1024;
  u16* attnb = xb;  // xb dead after QKV GEMM; reuse for attn output

  prep_kernel<<<3072, 256, 0, stream>>>(x, Wq, Wk, Wv, Wo, xb, WT);
  qkv_gemm_kernel<<<dim3(8, 32, 3), 512, 0, stream>>>(xb, WT, bq, bk, bv, Qb, Kb, Vb);
  attn_kernel<<<dim3(16, 16, 2), 512, 0, stream>>>(Qb, Kb, Vb, attnb);
  oproj_kernel<<<dim3(8, 64), 256, 0, stream>>>(attnb, WT + (size_t)3 * 1024 * 1024, bo, out);
}